// Round 7
// baseline (291.219 us; speedup 1.0000x reference)
//
#include <hip/hip_runtime.h>
#include <hip/hip_bf16.h>
#include <cstdint>

typedef float f32x4 __attribute__((ext_vector_type(4)));
typedef __bf16 bf16x8 __attribute__((ext_vector_type(8)));

#define BS 128
#define NSP 196
#define NTM 32
#define DDIM 768

__device__ inline ushort4 f4_to_bf4(float4 v)
{
    ushort4 u;
    u.x = __builtin_bit_cast(unsigned short, (__bf16)v.x);
    u.y = __builtin_bit_cast(unsigned short, (__bf16)v.y);
    u.z = __builtin_bit_cast(unsigned short, (__bf16)v.z);
    u.w = __builtin_bit_cast(unsigned short, (__bf16)v.w);
    return u;
}

__device__ inline bf16x8 f4x2_to_bf8(float4 lo, float4 hi)
{
    bf16x8 r;
    r[0] = (__bf16)lo.x; r[1] = (__bf16)lo.y; r[2] = (__bf16)lo.z; r[3] = (__bf16)lo.w;
    r[4] = (__bf16)hi.x; r[5] = (__bf16)hi.y; r[6] = (__bf16)hi.z; r[7] = (__bf16)hi.w;
    return r;
}

// ============ prep: row inv-norms for all 4 inputs (+ bf16 copies of sp) =====
// grid: [0,6272) sp1, [6272,12544) sp2, [12544,13568) tm1, [13568,14592) tm2
__global__ __launch_bounds__(256)
void prep_kernel(const float* __restrict__ sp1, const float* __restrict__ sp2,
                 const float* __restrict__ tm1, const float* __restrict__ tm2,
                 float* __restrict__ inx_sp, float* __restrict__ iny_sp,
                 float* __restrict__ inx_tm, float* __restrict__ iny_tm,
                 __bf16* __restrict__ X16, __bf16* __restrict__ Y16)
{
    int B = blockIdx.x;
    const float* src; float* inv; __bf16* dst;
    if (B < 6272)       {            src = sp1; inv = inx_sp; dst = X16; }
    else if (B < 12544) { B -= 6272; src = sp2; inv = iny_sp; dst = Y16; }
    else if (B < 13568) { B -= 12544; src = tm1; inv = inx_tm; dst = nullptr; }
    else                { B -= 13568; src = tm2; inv = iny_tm; dst = nullptr; }

    const int row  = B * 4 + (threadIdx.x >> 6);
    const int lane = threadIdx.x & 63;
    const float4* p = reinterpret_cast<const float4*>(src + (size_t)row * DDIM);
    float4 v[3];
    float ss = 0.f;
#pragma unroll
    for (int c = 0; c < 3; ++c) {
        v[c] = p[lane + 64 * c];
        ss = fmaf(v[c].x, v[c].x, ss); ss = fmaf(v[c].y, v[c].y, ss);
        ss = fmaf(v[c].z, v[c].z, ss); ss = fmaf(v[c].w, v[c].w, ss);
    }
#pragma unroll
    for (int off = 32; off; off >>= 1) ss += __shfl_xor(ss, off, 64);
    ss = __shfl(ss, 0, 64);
    if (lane == 0) inv[row] = 1.0f / (sqrtf(ss) + 1e-12f);
    if (dst) {
#pragma unroll
        for (int c = 0; c < 3; ++c)
            *reinterpret_cast<ushort4*>(&dst[(size_t)row * DDIM + lane * 4 + 256 * c]) = f4_to_bf4(v[c]);
    }
}

// ======================= spatial cost GEMM (bf16 inputs) =====================
// Grid 512 = 8 XCD * 16 batch * 4 coltile. Block 448 thr (7 waves).
// Tile 224x64, BK=64, dbuf LDS + XOR slot swizzle, 1 barrier pair / K-tile.
// A = exp(2*cos - 2) bf16 -> A_sp[b][224+pad rows][256 cols] (pre-zeroed).
#define GA_LDS 18432
__global__ __launch_bounds__(448)
void cost_gemm_sp16(const __bf16* __restrict__ X, const __bf16* __restrict__ Y,
                    const float* __restrict__ invx, const float* __restrict__ invy,
                    __bf16* __restrict__ Aout)
{
    __shared__ __bf16 lds[2 * GA_LDS];

    const int flat  = blockIdx.x;
    const int xcd   = flat & 7;
    const int s     = flat >> 3;
    const int b     = xcd * 16 + (s >> 2);
    const int ctile = s & 3;
    const int n0    = (ctile < 3) ? ctile * 64 : 132;

    const int tid  = threadIdx.x;
    const int w    = tid >> 6, lane = tid & 63;
    const int q    = lane >> 4, l16 = lane & 15;
    const int srow = tid >> 3;
    const int sslt = tid & 7;

    const __bf16* Yb = Y + (size_t)b * NSP * DDIM;

    bf16x8 aR[4], bR, b2R;

    auto LOADS = [&](int k0) {
#pragma unroll
        for (int p = 0; p < 4; ++p) {
            int gr = b * NSP + srow + 56 * p;
            gr = min(gr, BS * NSP - 1);
            aR[p] = *reinterpret_cast<const bf16x8*>(X + (size_t)gr * DDIM + k0 + sslt * 8);
        }
        bR = *reinterpret_cast<const bf16x8*>(Yb + (size_t)(n0 + srow) * DDIM + k0 + sslt * 8);
        if (tid < 64)
            b2R = *reinterpret_cast<const bf16x8*>(Yb + (size_t)(n0 + 56 + srow) * DDIM + k0 + sslt * 8);
    };
    auto WRITES = [&](int buf) {
#pragma unroll
        for (int p = 0; p < 4; ++p) {
            int r = srow + 56 * p;
            *reinterpret_cast<bf16x8*>(&lds[buf * GA_LDS + r * 64 + ((sslt ^ (r & 7)) << 3)]) = aR[p];
        }
        {
            int r = srow;
            *reinterpret_cast<bf16x8*>(&lds[buf * GA_LDS + 14336 + r * 64 + ((sslt ^ (r & 7)) << 3)]) = bR;
        }
        if (tid < 64) {
            int r = 56 + srow;
            *reinterpret_cast<bf16x8*>(&lds[buf * GA_LDS + 14336 + r * 64 + ((sslt ^ (r & 7)) << 3)]) = b2R;
        }
    };

    f32x4 acc[2][4];
#pragma unroll
    for (int i = 0; i < 2; ++i)
#pragma unroll
        for (int j = 0; j < 4; ++j) acc[i][j] = f32x4{0.f, 0.f, 0.f, 0.f};

    LOADS(0);
    int buf = 0;
    for (int kt = 0; kt < 12; ++kt) {
        WRITES(buf);
        if (kt < 11) LOADS((kt + 1) * 64);
        __syncthreads();
#pragma unroll
        for (int ks = 0; ks < 2; ++ks) {
            bf16x8 af[2], bf[4];
#pragma unroll
            for (int rt = 0; rt < 2; ++rt) {
                int r = w * 32 + rt * 16 + l16;
                af[rt] = *reinterpret_cast<const bf16x8*>(
                    &lds[buf * GA_LDS + r * 64 + (((ks * 4 + q) ^ (r & 7)) << 3)]);
            }
#pragma unroll
            for (int ct = 0; ct < 4; ++ct) {
                int r = ct * 16 + l16;
                bf[ct] = *reinterpret_cast<const bf16x8*>(
                    &lds[buf * GA_LDS + 14336 + r * 64 + (((ks * 4 + q) ^ (r & 7)) << 3)]);
            }
#pragma unroll
            for (int ct = 0; ct < 4; ++ct)
#pragma unroll
                for (int rt = 0; rt < 2; ++rt)
                    acc[rt][ct] = __builtin_amdgcn_mfma_f32_16x16x32_bf16(af[rt], bf[ct], acc[rt][ct], 0, 0, 0);
        }
        __syncthreads();
        buf ^= 1;
    }

    float ivy[4];
#pragma unroll
    for (int ct = 0; ct < 4; ++ct) ivy[ct] = invy[b * NSP + n0 + ct * 16 + l16];
#pragma unroll
    for (int rt = 0; rt < 2; ++rt)
#pragma unroll
        for (int rr = 0; rr < 4; ++rr) {
            int i = w * 32 + rt * 16 + q * 4 + rr;
            if (i < NSP) {
                float ivx = invx[b * NSP + i];
#pragma unroll
                for (int ct = 0; ct < 4; ++ct) {
                    int j = n0 + ct * 16 + l16;
                    float cs = acc[rt][ct][rr] * ivx * ivy[ct];
                    Aout[(size_t)b * 65536 + (size_t)i * 256 + j] = (__bf16)__expf(2.0f * cs - 2.0f);
                }
            }
        }
}

// ---------------- spatial cost GEMM, f32 inputs (ws fallback) ----------------
__global__ __launch_bounds__(448)
void cost_gemm_sp(const float* __restrict__ X, const float* __restrict__ Y,
                  const float* __restrict__ invx, const float* __restrict__ invy,
                  __bf16* __restrict__ Aout)
{
    __shared__ __bf16 lds[2 * GA_LDS];

    const int flat  = blockIdx.x;
    const int xcd   = flat & 7;
    const int s     = flat >> 3;
    const int b     = xcd * 16 + (s >> 2);
    const int ctile = s & 3;
    const int n0    = (ctile < 3) ? ctile * 64 : 132;

    const int tid  = threadIdx.x;
    const int w    = tid >> 6, lane = tid & 63;
    const int q    = lane >> 4, l16 = lane & 15;
    const int srow = tid >> 3;
    const int sslt = tid & 7;

    const float* Yb = Y + (size_t)b * NSP * DDIM;

    float4 aL[4], aH[4], bL, bH, b2L, b2H;

    auto LOADS = [&](int k0) {
#pragma unroll
        for (int p = 0; p < 4; ++p) {
            int gr = b * NSP + srow + 56 * p;
            gr = min(gr, BS * NSP - 1);
            const float* sp = X + (size_t)gr * DDIM + k0 + sslt * 8;
            aL[p] = *reinterpret_cast<const float4*>(sp);
            aH[p] = *reinterpret_cast<const float4*>(sp + 4);
        }
        {
            const float* sp = Yb + (size_t)(n0 + srow) * DDIM + k0 + sslt * 8;
            bL = *reinterpret_cast<const float4*>(sp);
            bH = *reinterpret_cast<const float4*>(sp + 4);
        }
        if (tid < 64) {
            const float* sp = Yb + (size_t)(n0 + 56 + srow) * DDIM + k0 + sslt * 8;
            b2L = *reinterpret_cast<const float4*>(sp);
            b2H = *reinterpret_cast<const float4*>(sp + 4);
        }
    };
    auto WRITES = [&](int buf) {
#pragma unroll
        for (int p = 0; p < 4; ++p) {
            int r = srow + 56 * p;
            *reinterpret_cast<bf16x8*>(&lds[buf * GA_LDS + r * 64 + ((sslt ^ (r & 7)) << 3)]) =
                f4x2_to_bf8(aL[p], aH[p]);
        }
        {
            int r = srow;
            *reinterpret_cast<bf16x8*>(&lds[buf * GA_LDS + 14336 + r * 64 + ((sslt ^ (r & 7)) << 3)]) =
                f4x2_to_bf8(bL, bH);
        }
        if (tid < 64) {
            int r = 56 + srow;
            *reinterpret_cast<bf16x8*>(&lds[buf * GA_LDS + 14336 + r * 64 + ((sslt ^ (r & 7)) << 3)]) =
                f4x2_to_bf8(b2L, b2H);
        }
    };

    f32x4 acc[2][4];
#pragma unroll
    for (int i = 0; i < 2; ++i)
#pragma unroll
        for (int j = 0; j < 4; ++j) acc[i][j] = f32x4{0.f, 0.f, 0.f, 0.f};

    LOADS(0);
    int buf = 0;
    for (int kt = 0; kt < 12; ++kt) {
        WRITES(buf);
        if (kt < 11) LOADS((kt + 1) * 64);
        __syncthreads();
#pragma unroll
        for (int ks = 0; ks < 2; ++ks) {
            bf16x8 af[2], bf[4];
#pragma unroll
            for (int rt = 0; rt < 2; ++rt) {
                int r = w * 32 + rt * 16 + l16;
                af[rt] = *reinterpret_cast<const bf16x8*>(
                    &lds[buf * GA_LDS + r * 64 + (((ks * 4 + q) ^ (r & 7)) << 3)]);
            }
#pragma unroll
            for (int ct = 0; ct < 4; ++ct) {
                int r = ct * 16 + l16;
                bf[ct] = *reinterpret_cast<const bf16x8*>(
                    &lds[buf * GA_LDS + 14336 + r * 64 + (((ks * 4 + q) ^ (r & 7)) << 3)]);
            }
#pragma unroll
            for (int ct = 0; ct < 4; ++ct)
#pragma unroll
                for (int rt = 0; rt < 2; ++rt)
                    acc[rt][ct] = __builtin_amdgcn_mfma_f32_16x16x32_bf16(af[rt], bf[ct], acc[rt][ct], 0, 0, 0);
        }
        __syncthreads();
        buf ^= 1;
    }

    float ivy[4];
#pragma unroll
    for (int ct = 0; ct < 4; ++ct) ivy[ct] = invy[b * NSP + n0 + ct * 16 + l16];
#pragma unroll
    for (int rt = 0; rt < 2; ++rt)
#pragma unroll
        for (int rr = 0; rr < 4; ++rr) {
            int i = w * 32 + rt * 16 + q * 4 + rr;
            if (i < NSP) {
                float ivx = invx[b * NSP + i];
#pragma unroll
                for (int ct = 0; ct < 4; ++ct) {
                    int j = n0 + ct * 16 + l16;
                    float cs = acc[rt][ct][rr] * ivx * ivy[ct];
                    Aout[(size_t)b * 65536 + (size_t)i * 256 + j] = (__bf16)__expf(2.0f * cs - 2.0f);
                }
            }
        }
}

// ---------------- temporal cost GEMM (f32 in/out) ----------------
template<int WROWS, int NWAVES, int BN, int NPTS>
__global__ __launch_bounds__(NWAVES * 64)
void cost_gemm(const float* __restrict__ X, const float* __restrict__ Y,
               const float* __restrict__ invx, const float* __restrict__ invy,
               float* __restrict__ Aout)
{
    constexpr int MT = WROWS * NWAVES;
    constexpr int CT = BN / 16;
    constexpr int RT = WROWS / 16;
    constexpr int KP = 40;
    constexpr int NTH = NWAVES * 64;
    __shared__ __bf16 As[MT][KP];
    __shared__ __bf16 Bs[BN][KP];

    const int b    = blockIdx.y;
    const int row0 = blockIdx.x * MT;
    const int tid  = threadIdx.x;
    const int w    = tid >> 6, lane = tid & 63;
    const int q    = lane >> 4, l16 = lane & 15;
    const float* Xb = X + (size_t)b * NPTS * DDIM;
    const float* Yb = Y + (size_t)b * NPTS * DDIM;

    f32x4 acc[RT][CT];
#pragma unroll
    for (int i = 0; i < RT; ++i)
#pragma unroll
        for (int j = 0; j < CT; ++j) acc[i][j] = f32x4{0.f, 0.f, 0.f, 0.f};

    for (int k0 = 0; k0 < DDIM; k0 += 32) {
        __syncthreads();
        for (int idx = tid * 4; idx < MT * 32; idx += NTH * 4) {
            int r = idx >> 5, kk = idx & 31;
            int gr = row0 + r;
            float4 v = {0.f, 0.f, 0.f, 0.f};
            if (gr < NPTS) v = *reinterpret_cast<const float4*>(Xb + (size_t)gr * DDIM + k0 + kk);
            *reinterpret_cast<ushort4*>(&As[r][kk]) = f4_to_bf4(v);
        }
        for (int idx = tid * 4; idx < BN * 32; idx += NTH * 4) {
            int r = idx >> 5, kk = idx & 31;
            float4 v = {0.f, 0.f, 0.f, 0.f};
            if (r < NPTS) v = *reinterpret_cast<const float4*>(Yb + (size_t)r * DDIM + k0 + kk);
            *reinterpret_cast<ushort4*>(&Bs[r][kk]) = f4_to_bf4(v);
        }
        __syncthreads();

        bf16x8 af[RT];
#pragma unroll
        for (int rt = 0; rt < RT; ++rt)
            af[rt] = *reinterpret_cast<const bf16x8*>(&As[w * WROWS + rt * 16 + l16][q * 8]);
#pragma unroll
        for (int ct = 0; ct < CT; ++ct) {
            bf16x8 bfr = *reinterpret_cast<const bf16x8*>(&Bs[ct * 16 + l16][q * 8]);
#pragma unroll
            for (int rt = 0; rt < RT; ++rt)
                acc[rt][ct] = __builtin_amdgcn_mfma_f32_16x16x32_bf16(af[rt], bfr, acc[rt][ct], 0, 0, 0);
        }
    }

#pragma unroll
    for (int rt = 0; rt < RT; ++rt)
#pragma unroll
        for (int ct = 0; ct < CT; ++ct)
#pragma unroll
            for (int rr = 0; rr < 4; ++rr) {
                int i = row0 + w * WROWS + rt * 16 + q * 4 + rr;
                int j = ct * 16 + l16;
                if (i < NPTS && j < NPTS) {
                    float g  = acc[rt][ct][rr];
                    float cs = g * invx[b * NPTS + i] * invy[b * NPTS + j];
                    Aout[(size_t)b * NPTS * NPTS + (size_t)i * NPTS + j] = expf(-2.0f * (1.0f - cs));
                }
            }
}

// ============ fused IPOT: blocks 0..127 spatial (1024 thr), 128..255 temporal =
// Spatial: lane (w 0..15, rq, cl) owns rows (rq+4w)+64k (k<3; w0 also 192+rq),
// cols {8cl+e, 8cl+128+e}. delta/sigma folded into P each iter (stable).
__global__ __launch_bounds__(1024, 4)
void ipot_all(const __bf16* __restrict__ Asp, const float* __restrict__ Atm,
              float* __restrict__ out)
{
    __shared__ float cpart[64 * 260];     // 66,560 B
    __shared__ float svec[2][272];
    __shared__ float wsum[16];

    const int B = blockIdx.x;
    if (B >= 128) {
        // ---- temporal: one wave, all-register ----
        if (threadIdx.x >= 64) return;
        const int b = B - 128;
        const float* Ab = Atm + (size_t)b * NTM * NTM;
        const int lane = threadIdx.x;
        const int rh = lane >> 5, cj = lane & 31;
        constexpr float MIU = 1.f / NTM;
        float A[16], P[16];
#pragma unroll
        for (int k = 0; k < 16; ++k) {
            A[k] = Ab[(rh + 2 * k) * NTM + cj];
            P[k] = 1.f;
        }
        float sv = MIU;
        for (int it = 0; it < 20; ++it) {
#pragma unroll
            for (int k = 0; k < 16; ++k) {
                P[k] *= A[k];
                float acc = P[k] * sv;
                acc += __shfl_xor(acc, 1);
                acc += __shfl_xor(acc, 2);
                acc += __shfl_xor(acc, 4);
                acc += __shfl_xor(acc, 8);
                acc += __shfl_xor(acc, 16);
                P[k] *= MIU / (acc + 1e-6f);
            }
            float cssum = 0.f;
#pragma unroll
            for (int k = 0; k < 16; ++k) cssum += P[k];
            cssum += __shfl_xor(cssum, 32);
            float sg = MIU / (cssum + 1e-6f);
#pragma unroll
            for (int k = 0; k < 16; ++k) P[k] *= sg;
            sv = sg;
        }
        float acc = 0.f;
#pragma unroll
        for (int k = 0; k < 16; ++k)
            acc = fmaf(P[k], -0.5f * __logf(A[k]), acc);
#pragma unroll
        for (int off = 32; off; off >>= 1) acc += __shfl_xor(acc, off);
        if (lane == 0) atomicAdd(out, -acc * (1.f / BS));
        return;
    }

    // ---- spatial ----
    const int b = (B & 7) * 16 + (B >> 3);     // XCD-home alignment with gemm
    const __bf16* Ab = Asp + (size_t)b * 65536;
    const int tid = threadIdx.x;
    const int w = tid >> 6, lane = tid & 63;
    const int rq = lane >> 4, cl = lane & 15;
    const int g = w * 4 + rq;                  // 0..63
    const int colbase = cl * 8;
    constexpr float MIU = 1.f / NSP;
    const bool w0 = (w == 0);

    float P[3][16], P3[16];
#pragma unroll
    for (int k = 0; k < 3; ++k)
#pragma unroll
        for (int e = 0; e < 16; ++e) P[k][e] = 1.f;
#pragma unroll
    for (int e = 0; e < 16; ++e) P3[e] = 1.f;

    float sr[16];
#pragma unroll
    for (int e = 0; e < 16; ++e) {
        int j = (e < 8) ? (colbase + e) : (colbase + 128 + (e - 8));
        sr[e] = (j < NSP) ? MIU : 0.f;
    }

    for (int it = 0; it < 20; ++it) {
        float cs[16];
#pragma unroll
        for (int e = 0; e < 16; ++e) cs[e] = 0.f;

#pragma unroll
        for (int k = 0; k < 3; ++k) {
            const __bf16* ap = Ab + (g + 64 * k) * 256 + colbase;
            bf16x8 a0 = *reinterpret_cast<const bf16x8*>(ap);
            bf16x8 a1 = *reinterpret_cast<const bf16x8*>(ap + 128);
            float racc = 0.f;
#pragma unroll
            for (int e = 0; e < 8; ++e) {
                P[k][e] *= (float)a0[e];
                racc = fmaf(P[k][e], sr[e], racc);
            }
#pragma unroll
            for (int e = 0; e < 8; ++e) {
                P[k][8 + e] *= (float)a1[e];
                racc = fmaf(P[k][8 + e], sr[8 + e], racc);
            }
            racc += __shfl_xor(racc, 1);
            racc += __shfl_xor(racc, 2);
            racc += __shfl_xor(racc, 4);
            racc += __shfl_xor(racc, 8);
            float delta = MIU / (racc + 1e-6f);
#pragma unroll
            for (int e = 0; e < 16; ++e) {
                P[k][e] *= delta;
                cs[e] += P[k][e];
            }
        }
        if (w0) {
            const __bf16* ap = Ab + (192 + rq) * 256 + colbase;
            bf16x8 a0 = *reinterpret_cast<const bf16x8*>(ap);
            bf16x8 a1 = *reinterpret_cast<const bf16x8*>(ap + 128);
            float racc = 0.f;
#pragma unroll
            for (int e = 0; e < 8; ++e) {
                P3[e] *= (float)a0[e];
                racc = fmaf(P3[e], sr[e], racc);
            }
#pragma unroll
            for (int e = 0; e < 8; ++e) {
                P3[8 + e] *= (float)a1[e];
                racc = fmaf(P3[8 + e], sr[8 + e], racc);
            }
            racc += __shfl_xor(racc, 1);
            racc += __shfl_xor(racc, 2);
            racc += __shfl_xor(racc, 4);
            racc += __shfl_xor(racc, 8);
            float delta = MIU / (racc + 1e-6f);
#pragma unroll
            for (int e = 0; e < 16; ++e) {
                P3[e] *= delta;
                cs[e] += P3[e];
            }
        }
        {
            float* cp = &cpart[g * 260 + colbase];
            *reinterpret_cast<f32x4*>(cp)     = f32x4{cs[0], cs[1], cs[2], cs[3]};
            *reinterpret_cast<f32x4*>(cp + 4) = f32x4{cs[4], cs[5], cs[6], cs[7]};
            float* cp2 = cp + 128;
            *reinterpret_cast<f32x4*>(cp2)     = f32x4{cs[8], cs[9], cs[10], cs[11]};
            *reinterpret_cast<f32x4*>(cp2 + 4) = f32x4{cs[12], cs[13], cs[14], cs[15]};
        }
        __syncthreads();
        if (tid < 256) {
            float s0 = 0.f, s1 = 0.f, s2 = 0.f, s3 = 0.f;
#pragma unroll
            for (int gg = 0; gg < 64; gg += 4) {
                s0 += cpart[(gg + 0) * 260 + tid];
                s1 += cpart[(gg + 1) * 260 + tid];
                s2 += cpart[(gg + 2) * 260 + tid];
                s3 += cpart[(gg + 3) * 260 + tid];
            }
            float sum = (s0 + s1) + (s2 + s3);
            svec[it & 1][tid] = (tid < NSP) ? (MIU / (sum + 1e-6f)) : 0.f;
        }
        __syncthreads();
        {
            const float* sv = svec[it & 1];
            f32x4 t0 = *reinterpret_cast<const f32x4*>(&sv[colbase]);
            f32x4 t1 = *reinterpret_cast<const f32x4*>(&sv[colbase + 4]);
            f32x4 t2 = *reinterpret_cast<const f32x4*>(&sv[colbase + 128]);
            f32x4 t3 = *reinterpret_cast<const f32x4*>(&sv[colbase + 132]);
            sr[0] = t0.x; sr[1] = t0.y; sr[2] = t0.z; sr[3] = t0.w;
            sr[4] = t1.x; sr[5] = t1.y; sr[6] = t1.z; sr[7] = t1.w;
            sr[8] = t2.x; sr[9] = t2.y; sr[10] = t2.z; sr[11] = t2.w;
            sr[12] = t3.x; sr[13] = t3.y; sr[14] = t3.z; sr[15] = t3.w;
        }
#pragma unroll
        for (int k = 0; k < 3; ++k)
#pragma unroll
            for (int e = 0; e < 16; ++e) P[k][e] *= sr[e];
#pragma unroll
        for (int e = 0; e < 16; ++e) P3[e] *= sr[e];
    }

    // loss: -sum T*C, C = -0.5*log(A)
    float acc = 0.f;
#pragma unroll
    for (int k = 0; k < 3; ++k) {
        const __bf16* ap = Ab + (g + 64 * k) * 256 + colbase;
        bf16x8 a0 = *reinterpret_cast<const bf16x8*>(ap);
        bf16x8 a1 = *reinterpret_cast<const bf16x8*>(ap + 128);
#pragma unroll
        for (int e = 0; e < 8; ++e) {
            acc = fmaf(P[k][e],     -0.5f * __logf(fmaxf((float)a0[e], 1e-30f)), acc);
            acc = fmaf(P[k][8 + e], -0.5f * __logf(fmaxf((float)a1[e], 1e-30f)), acc);
        }
    }
    if (w0) {
        const __bf16* ap = Ab + (192 + rq) * 256 + colbase;
        bf16x8 a0 = *reinterpret_cast<const bf16x8*>(ap);
        bf16x8 a1 = *reinterpret_cast<const bf16x8*>(ap + 128);
#pragma unroll
        for (int e = 0; e < 8; ++e) {
            acc = fmaf(P3[e],     -0.5f * __logf(fmaxf((float)a0[e], 1e-30f)), acc);
            acc = fmaf(P3[8 + e], -0.5f * __logf(fmaxf((float)a1[e], 1e-30f)), acc);
        }
    }
#pragma unroll
    for (int off = 32; off; off >>= 1) acc += __shfl_xor(acc, off);
    if (lane == 0) wsum[w] = acc;
    __syncthreads();
    if (tid == 0) {
        float t = 0.f;
#pragma unroll
        for (int i = 0; i < 16; ++i) t += wsum[i];
        atomicAdd(out, -t * (1.f / BS));
    }
}

extern "C" void kernel_launch(void* const* d_in, const int* in_sizes, int n_in,
                              void* d_out, int out_size, void* d_ws, size_t ws_size,
                              hipStream_t stream)
{
    const float* sp1 = (const float*)d_in[0];
    const float* sp2 = (const float*)d_in[1];
    const float* tm1 = (const float*)d_in[2];
    const float* tm2 = (const float*)d_in[3];
    float* out = (float*)d_out;
    float* ws  = (float*)d_ws;

    float* inx_sp = ws;                          // 25088
    float* iny_sp = inx_sp + BS * NSP;           // 25088
    float* inx_tm = iny_sp + BS * NSP;           // 4096
    float* iny_tm = inx_tm + BS * NTM;           // 4096
    float* A_tm   = iny_tm + BS * NTM;           // 131072 f32
    __bf16* A_sp  = (__bf16*)(ws + 189440);      // 33,554,432 B
    char*   base  = (char*)d_ws;
    __bf16* X16   = (__bf16*)(base + 34312192);  // 38,535,168 B
    __bf16* Y16   = (__bf16*)(base + 72847360);  // 38,535,168 B
    const size_t NEED = 111382528;
    const bool fast = (ws_size >= NEED);

    prep_kernel<<<dim3(14592), 256, 0, stream>>>(sp1, sp2, tm1, tm2,
                                                 inx_sp, iny_sp, inx_tm, iny_tm,
                                                 fast ? X16 : nullptr, fast ? Y16 : nullptr);

    (void)hipMemsetAsync(A_sp, 0, (size_t)BS * 65536 * 2, stream);

    if (fast)
        cost_gemm_sp16<<<dim3(512), 448, 0, stream>>>(X16, Y16, inx_sp, iny_sp, A_sp);
    else
        cost_gemm_sp<<<dim3(512), 448, 0, stream>>>(sp1, sp2, inx_sp, iny_sp, A_sp);

    cost_gemm<16, 2, 32, NTM><<<dim3(1, BS), 128, 0, stream>>>(tm1, tm2, inx_tm, iny_tm, A_tm);

    (void)hipMemsetAsync(d_out, 0, sizeof(float), stream);

    ipot_all<<<dim3(256), 1024, 0, stream>>>(A_sp, A_tm, out);
}

// Round 8
// 174.206 us; speedup vs baseline: 1.6717x; 1.6717x over previous
//
#include <hip/hip_runtime.h>
#include <hip/hip_bf16.h>
#include <cstdint>

typedef float f32x4 __attribute__((ext_vector_type(4)));
typedef __bf16 bf16x8 __attribute__((ext_vector_type(8)));

#define BS 128
#define NSP 196
#define NTM 32
#define DDIM 768

__device__ inline ushort4 f4_to_bf4(float4 v)
{
    ushort4 u;
    u.x = __builtin_bit_cast(unsigned short, (__bf16)v.x);
    u.y = __builtin_bit_cast(unsigned short, (__bf16)v.y);
    u.z = __builtin_bit_cast(unsigned short, (__bf16)v.z);
    u.w = __builtin_bit_cast(unsigned short, (__bf16)v.w);
    return u;
}

__device__ inline bf16x8 f4x2_to_bf8(float4 lo, float4 hi)
{
    bf16x8 r;
    r[0] = (__bf16)lo.x; r[1] = (__bf16)lo.y; r[2] = (__bf16)lo.z; r[3] = (__bf16)lo.w;
    r[4] = (__bf16)hi.x; r[5] = (__bf16)hi.y; r[6] = (__bf16)hi.z; r[7] = (__bf16)hi.w;
    return r;
}

// ============ prep: row inv-norms for all 4 inputs (+ bf16 copies of sp) =====
__global__ __launch_bounds__(256)
void prep_kernel(const float* __restrict__ sp1, const float* __restrict__ sp2,
                 const float* __restrict__ tm1, const float* __restrict__ tm2,
                 float* __restrict__ inx_sp, float* __restrict__ iny_sp,
                 float* __restrict__ inx_tm, float* __restrict__ iny_tm,
                 __bf16* __restrict__ X16, __bf16* __restrict__ Y16)
{
    int B = blockIdx.x;
    const float* src; float* inv; __bf16* dst;
    if (B < 6272)       {            src = sp1; inv = inx_sp; dst = X16; }
    else if (B < 12544) { B -= 6272; src = sp2; inv = iny_sp; dst = Y16; }
    else if (B < 13568) { B -= 12544; src = tm1; inv = inx_tm; dst = nullptr; }
    else                { B -= 13568; src = tm2; inv = iny_tm; dst = nullptr; }

    const int row  = B * 4 + (threadIdx.x >> 6);
    const int lane = threadIdx.x & 63;
    const float4* p = reinterpret_cast<const float4*>(src + (size_t)row * DDIM);
    float4 v[3];
    float ss = 0.f;
#pragma unroll
    for (int c = 0; c < 3; ++c) {
        v[c] = p[lane + 64 * c];
        ss = fmaf(v[c].x, v[c].x, ss); ss = fmaf(v[c].y, v[c].y, ss);
        ss = fmaf(v[c].z, v[c].z, ss); ss = fmaf(v[c].w, v[c].w, ss);
    }
#pragma unroll
    for (int off = 32; off; off >>= 1) ss += __shfl_xor(ss, off, 64);
    if (lane == 0) inv[row] = 1.0f / (sqrtf(ss) + 1e-12f);
    if (dst) {
#pragma unroll
        for (int c = 0; c < 3; ++c)
            *reinterpret_cast<ushort4*>(&dst[(size_t)row * DDIM + lane * 4 + 256 * c]) = f4_to_bf4(v[c]);
    }
}

// ======================= spatial cost GEMM (bf16 inputs) =====================
#define GA_LDS 18432
__global__ __launch_bounds__(448)
void cost_gemm_sp16(const __bf16* __restrict__ X, const __bf16* __restrict__ Y,
                    const float* __restrict__ invx, const float* __restrict__ invy,
                    __bf16* __restrict__ Aout)
{
    __shared__ __bf16 lds[2 * GA_LDS];

    const int flat  = blockIdx.x;
    const int xcd   = flat & 7;
    const int s     = flat >> 3;
    const int b     = xcd * 16 + (s >> 2);
    const int ctile = s & 3;
    const int n0    = (ctile < 3) ? ctile * 64 : 132;

    const int tid  = threadIdx.x;
    const int w    = tid >> 6, lane = tid & 63;
    const int q    = lane >> 4, l16 = lane & 15;
    const int srow = tid >> 3;
    const int sslt = tid & 7;

    const __bf16* Yb = Y + (size_t)b * NSP * DDIM;

    bf16x8 aR[4], bR, b2R;

    auto LOADS = [&](int k0) {
#pragma unroll
        for (int p = 0; p < 4; ++p) {
            int gr = b * NSP + srow + 56 * p;
            gr = min(gr, BS * NSP - 1);
            aR[p] = *reinterpret_cast<const bf16x8*>(X + (size_t)gr * DDIM + k0 + sslt * 8);
        }
        bR = *reinterpret_cast<const bf16x8*>(Yb + (size_t)(n0 + srow) * DDIM + k0 + sslt * 8);
        if (tid < 64)
            b2R = *reinterpret_cast<const bf16x8*>(Yb + (size_t)(n0 + 56 + srow) * DDIM + k0 + sslt * 8);
    };
    auto WRITES = [&](int buf) {
#pragma unroll
        for (int p = 0; p < 4; ++p) {
            int r = srow + 56 * p;
            *reinterpret_cast<bf16x8*>(&lds[buf * GA_LDS + r * 64 + ((sslt ^ (r & 7)) << 3)]) = aR[p];
        }
        {
            int r = srow;
            *reinterpret_cast<bf16x8*>(&lds[buf * GA_LDS + 14336 + r * 64 + ((sslt ^ (r & 7)) << 3)]) = bR;
        }
        if (tid < 64) {
            int r = 56 + srow;
            *reinterpret_cast<bf16x8*>(&lds[buf * GA_LDS + 14336 + r * 64 + ((sslt ^ (r & 7)) << 3)]) = b2R;
        }
    };

    f32x4 acc[2][4];
#pragma unroll
    for (int i = 0; i < 2; ++i)
#pragma unroll
        for (int j = 0; j < 4; ++j) acc[i][j] = f32x4{0.f, 0.f, 0.f, 0.f};

    LOADS(0);
    int buf = 0;
    for (int kt = 0; kt < 12; ++kt) {
        WRITES(buf);
        if (kt < 11) LOADS((kt + 1) * 64);
        __syncthreads();
#pragma unroll
        for (int ks = 0; ks < 2; ++ks) {
            bf16x8 af[2], bf[4];
#pragma unroll
            for (int rt = 0; rt < 2; ++rt) {
                int r = w * 32 + rt * 16 + l16;
                af[rt] = *reinterpret_cast<const bf16x8*>(
                    &lds[buf * GA_LDS + r * 64 + (((ks * 4 + q) ^ (r & 7)) << 3)]);
            }
#pragma unroll
            for (int ct = 0; ct < 4; ++ct) {
                int r = ct * 16 + l16;
                bf[ct] = *reinterpret_cast<const bf16x8*>(
                    &lds[buf * GA_LDS + 14336 + r * 64 + (((ks * 4 + q) ^ (r & 7)) << 3)]);
            }
#pragma unroll
            for (int ct = 0; ct < 4; ++ct)
#pragma unroll
                for (int rt = 0; rt < 2; ++rt)
                    acc[rt][ct] = __builtin_amdgcn_mfma_f32_16x16x32_bf16(af[rt], bf[ct], acc[rt][ct], 0, 0, 0);
        }
        __syncthreads();
        buf ^= 1;
    }

    float ivy[4];
#pragma unroll
    for (int ct = 0; ct < 4; ++ct) ivy[ct] = invy[b * NSP + n0 + ct * 16 + l16];
#pragma unroll
    for (int rt = 0; rt < 2; ++rt)
#pragma unroll
        for (int rr = 0; rr < 4; ++rr) {
            int i = w * 32 + rt * 16 + q * 4 + rr;
            if (i < NSP) {
                float ivx = invx[b * NSP + i];
#pragma unroll
                for (int ct = 0; ct < 4; ++ct) {
                    int j = n0 + ct * 16 + l16;
                    float cs = acc[rt][ct][rr] * ivx * ivy[ct];
                    Aout[(size_t)b * 65536 + (size_t)i * 256 + j] = (__bf16)__expf(2.0f * cs - 2.0f);
                }
            }
        }
}

// ---------------- spatial cost GEMM, f32 inputs (ws fallback) ----------------
__global__ __launch_bounds__(448)
void cost_gemm_sp(const float* __restrict__ X, const float* __restrict__ Y,
                  const float* __restrict__ invx, const float* __restrict__ invy,
                  __bf16* __restrict__ Aout)
{
    __shared__ __bf16 lds[2 * GA_LDS];

    const int flat  = blockIdx.x;
    const int xcd   = flat & 7;
    const int s     = flat >> 3;
    const int b     = xcd * 16 + (s >> 2);
    const int ctile = s & 3;
    const int n0    = (ctile < 3) ? ctile * 64 : 132;

    const int tid  = threadIdx.x;
    const int w    = tid >> 6, lane = tid & 63;
    const int q    = lane >> 4, l16 = lane & 15;
    const int srow = tid >> 3;
    const int sslt = tid & 7;

    const float* Yb = Y + (size_t)b * NSP * DDIM;

    float4 aL[4], aH[4], bL, bH, b2L, b2H;

    auto LOADS = [&](int k0) {
#pragma unroll
        for (int p = 0; p < 4; ++p) {
            int gr = b * NSP + srow + 56 * p;
            gr = min(gr, BS * NSP - 1);
            const float* sp = X + (size_t)gr * DDIM + k0 + sslt * 8;
            aL[p] = *reinterpret_cast<const float4*>(sp);
            aH[p] = *reinterpret_cast<const float4*>(sp + 4);
        }
        {
            const float* sp = Yb + (size_t)(n0 + srow) * DDIM + k0 + sslt * 8;
            bL = *reinterpret_cast<const float4*>(sp);
            bH = *reinterpret_cast<const float4*>(sp + 4);
        }
        if (tid < 64) {
            const float* sp = Yb + (size_t)(n0 + 56 + srow) * DDIM + k0 + sslt * 8;
            b2L = *reinterpret_cast<const float4*>(sp);
            b2H = *reinterpret_cast<const float4*>(sp + 4);
        }
    };
    auto WRITES = [&](int buf) {
#pragma unroll
        for (int p = 0; p < 4; ++p) {
            int r = srow + 56 * p;
            *reinterpret_cast<bf16x8*>(&lds[buf * GA_LDS + r * 64 + ((sslt ^ (r & 7)) << 3)]) =
                f4x2_to_bf8(aL[p], aH[p]);
        }
        {
            int r = srow;
            *reinterpret_cast<bf16x8*>(&lds[buf * GA_LDS + 14336 + r * 64 + ((sslt ^ (r & 7)) << 3)]) =
                f4x2_to_bf8(bL, bH);
        }
        if (tid < 64) {
            int r = 56 + srow;
            *reinterpret_cast<bf16x8*>(&lds[buf * GA_LDS + 14336 + r * 64 + ((sslt ^ (r & 7)) << 3)]) =
                f4x2_to_bf8(b2L, b2H);
        }
    };

    f32x4 acc[2][4];
#pragma unroll
    for (int i = 0; i < 2; ++i)
#pragma unroll
        for (int j = 0; j < 4; ++j) acc[i][j] = f32x4{0.f, 0.f, 0.f, 0.f};

    LOADS(0);
    int buf = 0;
    for (int kt = 0; kt < 12; ++kt) {
        WRITES(buf);
        if (kt < 11) LOADS((kt + 1) * 64);
        __syncthreads();
#pragma unroll
        for (int ks = 0; ks < 2; ++ks) {
            bf16x8 af[2], bf[4];
#pragma unroll
            for (int rt = 0; rt < 2; ++rt) {
                int r = w * 32 + rt * 16 + l16;
                af[rt] = *reinterpret_cast<const bf16x8*>(
                    &lds[buf * GA_LDS + r * 64 + (((ks * 4 + q) ^ (r & 7)) << 3)]);
            }
#pragma unroll
            for (int ct = 0; ct < 4; ++ct) {
                int r = ct * 16 + l16;
                bf[ct] = *reinterpret_cast<const bf16x8*>(
                    &lds[buf * GA_LDS + 14336 + r * 64 + (((ks * 4 + q) ^ (r & 7)) << 3)]);
            }
#pragma unroll
            for (int ct = 0; ct < 4; ++ct)
#pragma unroll
                for (int rt = 0; rt < 2; ++rt)
                    acc[rt][ct] = __builtin_amdgcn_mfma_f32_16x16x32_bf16(af[rt], bf[ct], acc[rt][ct], 0, 0, 0);
        }
        __syncthreads();
        buf ^= 1;
    }

    float ivy[4];
#pragma unroll
    for (int ct = 0; ct < 4; ++ct) ivy[ct] = invy[b * NSP + n0 + ct * 16 + l16];
#pragma unroll
    for (int rt = 0; rt < 2; ++rt)
#pragma unroll
        for (int rr = 0; rr < 4; ++rr) {
            int i = w * 32 + rt * 16 + q * 4 + rr;
            if (i < NSP) {
                float ivx = invx[b * NSP + i];
#pragma unroll
                for (int ct = 0; ct < 4; ++ct) {
                    int j = n0 + ct * 16 + l16;
                    float cs = acc[rt][ct][rr] * ivx * ivy[ct];
                    Aout[(size_t)b * 65536 + (size_t)i * 256 + j] = (__bf16)__expf(2.0f * cs - 2.0f);
                }
            }
        }
}

// ---------------- temporal cost GEMM (f32 in/out) ----------------
template<int WROWS, int NWAVES, int BN, int NPTS>
__global__ __launch_bounds__(NWAVES * 64)
void cost_gemm(const float* __restrict__ X, const float* __restrict__ Y,
               const float* __restrict__ invx, const float* __restrict__ invy,
               float* __restrict__ Aout)
{
    constexpr int MT = WROWS * NWAVES;
    constexpr int CT = BN / 16;
    constexpr int RT = WROWS / 16;
    constexpr int KP = 40;
    constexpr int NTH = NWAVES * 64;
    __shared__ __bf16 As[MT][KP];
    __shared__ __bf16 Bs[BN][KP];

    const int b    = blockIdx.y;
    const int row0 = blockIdx.x * MT;
    const int tid  = threadIdx.x;
    const int w    = tid >> 6, lane = tid & 63;
    const int q    = lane >> 4, l16 = lane & 15;
    const float* Xb = X + (size_t)b * NPTS * DDIM;
    const float* Yb = Y + (size_t)b * NPTS * DDIM;

    f32x4 acc[RT][CT];
#pragma unroll
    for (int i = 0; i < RT; ++i)
#pragma unroll
        for (int j = 0; j < CT; ++j) acc[i][j] = f32x4{0.f, 0.f, 0.f, 0.f};

    for (int k0 = 0; k0 < DDIM; k0 += 32) {
        __syncthreads();
        for (int idx = tid * 4; idx < MT * 32; idx += NTH * 4) {
            int r = idx >> 5, kk = idx & 31;
            int gr = row0 + r;
            float4 v = {0.f, 0.f, 0.f, 0.f};
            if (gr < NPTS) v = *reinterpret_cast<const float4*>(Xb + (size_t)gr * DDIM + k0 + kk);
            *reinterpret_cast<ushort4*>(&As[r][kk]) = f4_to_bf4(v);
        }
        for (int idx = tid * 4; idx < BN * 32; idx += NTH * 4) {
            int r = idx >> 5, kk = idx & 31;
            float4 v = {0.f, 0.f, 0.f, 0.f};
            if (r < NPTS) v = *reinterpret_cast<const float4*>(Yb + (size_t)r * DDIM + k0 + kk);
            *reinterpret_cast<ushort4*>(&Bs[r][kk]) = f4_to_bf4(v);
        }
        __syncthreads();

        bf16x8 af[RT];
#pragma unroll
        for (int rt = 0; rt < RT; ++rt)
            af[rt] = *reinterpret_cast<const bf16x8*>(&As[w * WROWS + rt * 16 + l16][q * 8]);
#pragma unroll
        for (int ct = 0; ct < CT; ++ct) {
            bf16x8 bfr = *reinterpret_cast<const bf16x8*>(&Bs[ct * 16 + l16][q * 8]);
#pragma unroll
            for (int rt = 0; rt < RT; ++rt)
                acc[rt][ct] = __builtin_amdgcn_mfma_f32_16x16x32_bf16(af[rt], bfr, acc[rt][ct], 0, 0, 0);
        }
    }

#pragma unroll
    for (int rt = 0; rt < RT; ++rt)
#pragma unroll
        for (int ct = 0; ct < CT; ++ct)
#pragma unroll
            for (int rr = 0; rr < 4; ++rr) {
                int i = row0 + w * WROWS + rt * 16 + q * 4 + rr;
                int j = ct * 16 + l16;
                if (i < NPTS && j < NPTS) {
                    float g  = acc[rt][ct][rr];
                    float cs = g * invx[b * NPTS + i] * invy[b * NPTS + j];
                    Aout[(size_t)b * NPTS * NPTS + (size_t)i * NPTS + j] = expf(-2.0f * (1.0f - cs));
                }
            }
}

// ========== fused IPOT: blocks 0..127 spatial (A in LDS), 128..255 temporal ==
// Spatial: 512 thr, lane (w, rq, cl) owns rows (w*4+rq)+32k (k<7), cols
// {8cl+e, 8cl+128+e}. delta/sigma folded into P each iter (stable recursion).
// __launch_bounds__(512,1): 2 waves/SIMD -> 256-VGPR cap, no spill.
__global__ __launch_bounds__(512, 1)
void ipot_lds(const __bf16* __restrict__ Asp, const float* __restrict__ Atm,
              float* __restrict__ out)
{
    __shared__ __bf16 Alds[224 * 256];    // 114,688 B
    __shared__ float  cpart[32 * 260];    //  33,280 B
    __shared__ float  svec[2][272];
    __shared__ float  wsum[8];

    const int B = blockIdx.x;
    if (B >= 128) {
        // ---- temporal: one wave, all-register ----
        if (threadIdx.x >= 64) return;
        const int b = B - 128;
        const float* Ab = Atm + (size_t)b * NTM * NTM;
        const int lane = threadIdx.x;
        const int rh = lane >> 5, cj = lane & 31;
        constexpr float MIU = 1.f / NTM;
        float A[16], P[16];
#pragma unroll
        for (int k = 0; k < 16; ++k) {
            A[k] = Ab[(rh + 2 * k) * NTM + cj];
            P[k] = 1.f;
        }
        float sv = MIU;
        for (int it = 0; it < 20; ++it) {
#pragma unroll
            for (int k = 0; k < 16; ++k) {
                P[k] *= A[k];
                float acc = P[k] * sv;
                acc += __shfl_xor(acc, 1);
                acc += __shfl_xor(acc, 2);
                acc += __shfl_xor(acc, 4);
                acc += __shfl_xor(acc, 8);
                acc += __shfl_xor(acc, 16);
                P[k] *= MIU / (acc + 1e-6f);
            }
            float cssum = 0.f;
#pragma unroll
            for (int k = 0; k < 16; ++k) cssum += P[k];
            cssum += __shfl_xor(cssum, 32);
            float sg = MIU / (cssum + 1e-6f);
#pragma unroll
            for (int k = 0; k < 16; ++k) P[k] *= sg;
            sv = sg;
        }
        float acc = 0.f;
#pragma unroll
        for (int k = 0; k < 16; ++k)
            acc = fmaf(P[k], -0.5f * __logf(A[k]), acc);
#pragma unroll
        for (int off = 32; off; off >>= 1) acc += __shfl_xor(acc, off);
        if (lane == 0) atomicAdd(out, -acc * (1.f / BS));
        return;
    }

    // ---- spatial ----
    const int b = (B & 7) * 16 + (B >> 3);     // XCD-home alignment with gemm
    const __bf16* Ab = Asp + (size_t)b * 65536;
    const int tid = threadIdx.x;
    const int w = tid >> 6, lane = tid & 63;
    const int rq = lane >> 4, cl = lane & 15;
    const int g = w * 4 + rq;                  // 0..31
    const int colbase = cl * 8;
    constexpr float MIU = 1.f / NSP;

    // stage A (rows 0..195) into LDS; zero rows 196..223
    for (int idx = tid; idx < NSP * 32; idx += 512) {
        int r = idx >> 5, c8 = (idx & 31) << 3;
        *reinterpret_cast<bf16x8*>(&Alds[r * 256 + c8]) =
            *reinterpret_cast<const bf16x8*>(&Ab[(size_t)r * 256 + c8]);
    }
    {
        ushort4 z = {0, 0, 0, 0};
        for (int idx = tid; idx < 28 * 64; idx += 512) {
            int r = 196 + (idx >> 6), c4 = (idx & 63) << 2;
            *reinterpret_cast<ushort4*>(&Alds[r * 256 + c4]) = z;
        }
    }
    __syncthreads();

    float P[7][16];
#pragma unroll
    for (int k = 0; k < 7; ++k)
#pragma unroll
        for (int e = 0; e < 16; ++e) P[k][e] = 1.f;

    float sr[16];
#pragma unroll
    for (int e = 0; e < 16; ++e) {
        int j = (e < 8) ? (colbase + e) : (colbase + 128 + (e - 8));
        sr[e] = (j < NSP) ? MIU : 0.f;
    }

    for (int it = 0; it < 20; ++it) {
        float cs[16];
#pragma unroll
        for (int e = 0; e < 16; ++e) cs[e] = 0.f;

#pragma unroll
        for (int k = 0; k < 7; ++k) {
            const __bf16* ap = &Alds[(g + 32 * k) * 256 + colbase];
            bf16x8 a0 = *reinterpret_cast<const bf16x8*>(ap);
            bf16x8 a1 = *reinterpret_cast<const bf16x8*>(ap + 128);
            float racc = 0.f;
#pragma unroll
            for (int e = 0; e < 8; ++e) {
                P[k][e] *= (float)a0[e];
                racc = fmaf(P[k][e], sr[e], racc);
            }
#pragma unroll
            for (int e = 0; e < 8; ++e) {
                P[k][8 + e] *= (float)a1[e];
                racc = fmaf(P[k][8 + e], sr[8 + e], racc);
            }
            racc += __shfl_xor(racc, 1);
            racc += __shfl_xor(racc, 2);
            racc += __shfl_xor(racc, 4);
            racc += __shfl_xor(racc, 8);
            float delta = MIU / (racc + 1e-6f);
#pragma unroll
            for (int e = 0; e < 16; ++e) {
                P[k][e] *= delta;
                cs[e] += P[k][e];
            }
        }
        {
            float* cp = &cpart[g * 260 + colbase];
            *reinterpret_cast<f32x4*>(cp)     = f32x4{cs[0], cs[1], cs[2], cs[3]};
            *reinterpret_cast<f32x4*>(cp + 4) = f32x4{cs[4], cs[5], cs[6], cs[7]};
            float* cp2 = cp + 128;
            *reinterpret_cast<f32x4*>(cp2)     = f32x4{cs[8], cs[9], cs[10], cs[11]};
            *reinterpret_cast<f32x4*>(cp2 + 4) = f32x4{cs[12], cs[13], cs[14], cs[15]};
        }
        __syncthreads();
        if (tid < 256) {
            float s0 = 0.f, s1 = 0.f, s2 = 0.f, s3 = 0.f;
#pragma unroll
            for (int gg = 0; gg < 32; gg += 4) {
                s0 += cpart[(gg + 0) * 260 + tid];
                s1 += cpart[(gg + 1) * 260 + tid];
                s2 += cpart[(gg + 2) * 260 + tid];
                s3 += cpart[(gg + 3) * 260 + tid];
            }
            float sum = (s0 + s1) + (s2 + s3);
            svec[it & 1][tid] = (tid < NSP) ? (MIU / (sum + 1e-6f)) : 0.f;
        }
        __syncthreads();
        {
            const float* sv = svec[it & 1];
            f32x4 t0 = *reinterpret_cast<const f32x4*>(&sv[colbase]);
            f32x4 t1 = *reinterpret_cast<const f32x4*>(&sv[colbase + 4]);
            f32x4 t2 = *reinterpret_cast<const f32x4*>(&sv[colbase + 128]);
            f32x4 t3 = *reinterpret_cast<const f32x4*>(&sv[colbase + 132]);
            sr[0] = t0.x; sr[1] = t0.y; sr[2] = t0.z; sr[3] = t0.w;
            sr[4] = t1.x; sr[5] = t1.y; sr[6] = t1.z; sr[7] = t1.w;
            sr[8] = t2.x; sr[9] = t2.y; sr[10] = t2.z; sr[11] = t2.w;
            sr[12] = t3.x; sr[13] = t3.y; sr[14] = t3.z; sr[15] = t3.w;
        }
#pragma unroll
        for (int k = 0; k < 7; ++k)
#pragma unroll
            for (int e = 0; e < 16; ++e) P[k][e] *= sr[e];
    }

    // loss: -sum T*C, C = -0.5*log(A)
    float acc = 0.f;
#pragma unroll
    for (int k = 0; k < 7; ++k) {
        const __bf16* ap = &Alds[(g + 32 * k) * 256 + colbase];
        bf16x8 a0 = *reinterpret_cast<const bf16x8*>(ap);
        bf16x8 a1 = *reinterpret_cast<const bf16x8*>(ap + 128);
#pragma unroll
        for (int e = 0; e < 8; ++e) {
            acc = fmaf(P[k][e],     -0.5f * __logf(fmaxf((float)a0[e], 1e-30f)), acc);
            acc = fmaf(P[k][8 + e], -0.5f * __logf(fmaxf((float)a1[e], 1e-30f)), acc);
        }
    }
#pragma unroll
    for (int off = 32; off; off >>= 1) acc += __shfl_xor(acc, off);
    if (lane == 0) wsum[w] = acc;
    __syncthreads();
    if (tid == 0) {
        float t = 0.f;
#pragma unroll
        for (int i = 0; i < 8; ++i) t += wsum[i];
        atomicAdd(out, -t * (1.f / BS));
    }
}

extern "C" void kernel_launch(void* const* d_in, const int* in_sizes, int n_in,
                              void* d_out, int out_size, void* d_ws, size_t ws_size,
                              hipStream_t stream)
{
    const float* sp1 = (const float*)d_in[0];
    const float* sp2 = (const float*)d_in[1];
    const float* tm1 = (const float*)d_in[2];
    const float* tm2 = (const float*)d_in[3];
    float* out = (float*)d_out;
    float* ws  = (float*)d_ws;

    float* inx_sp = ws;
    float* iny_sp = inx_sp + BS * NSP;
    float* inx_tm = iny_sp + BS * NSP;
    float* iny_tm = inx_tm + BS * NTM;
    float* A_tm   = iny_tm + BS * NTM;
    __bf16* A_sp  = (__bf16*)(ws + 189440);      // 33,554,432 B
    char*   base  = (char*)d_ws;
    __bf16* X16   = (__bf16*)(base + 34312192);  // 38,535,168 B
    __bf16* Y16   = (__bf16*)(base + 72847360);  // 38,535,168 B
    const size_t NEED = 111382528;
    const bool fast = (ws_size >= NEED);

    prep_kernel<<<dim3(14592), 256, 0, stream>>>(sp1, sp2, tm1, tm2,
                                                 inx_sp, iny_sp, inx_tm, iny_tm,
                                                 fast ? X16 : nullptr, fast ? Y16 : nullptr);

    (void)hipMemsetAsync(A_sp, 0, (size_t)BS * 65536 * 2, stream);

    if (fast)
        cost_gemm_sp16<<<dim3(512), 448, 0, stream>>>(X16, Y16, inx_sp, iny_sp, A_sp);
    else
        cost_gemm_sp<<<dim3(512), 448, 0, stream>>>(sp1, sp2, inx_sp, iny_sp, A_sp);

    cost_gemm<16, 2, 32, NTM><<<dim3(1, BS), 128, 0, stream>>>(tm1, tm2, inx_tm, iny_tm, A_tm);

    (void)hipMemsetAsync(d_out, 0, sizeof(float), stream);

    ipot_lds<<<dim3(256), 512, 0, stream>>>(A_sp, A_tm, out);
}